// Round 3
// baseline (451.871 us; speedup 1.0000x reference)
//
#include <hip/hip_runtime.h>

#define NUM_FACTORS 39
#define EMB_DIM 64
#define ROWS_PER_BLOCK 4   // 4 waves of 64 = 256 threads

// CALIBRATION ROUND: kernel body identical to round 2; kernel_launch issues
// it 4x (idempotent) so T_kernel = (dur_us - 334)/3 becomes measurable
// around the ~300us of harness reset traffic that dominates dur_us.
__global__ __launch_bounds__(256, 8) void fwfm_kernel(
    const int* __restrict__ x,            // (B, 39) int32
    const float* __restrict__ w0,         // (1,)
    const float* __restrict__ bias_table, // (1M, 1)
    const float* __restrict__ emb_table,  // (1M, 64)
    const float* __restrict__ W,          // (39, 39)
    float* __restrict__ out,              // (B,)
    int batch)
{
    const int lane = threadIdx.x & 63;
    const int wave = threadIdx.x >> 6;
    const int row  = blockIdx.x * ROWS_PER_BLOCK + wave;
    if (row >= batch) return;

    // Lane i (i<39) loads this row's i-th field index and its bias.
    int myidx = 0;
    float bpart = 0.0f;
    if (lane < NUM_FACTORS) {
        myidx = x[row * NUM_FACTORS + lane];
        bpart = bias_table[myidx];
    }

    // Gather embeddings: e[i] = emb_table[idx_i][lane].
    // readlane -> SGPR row index -> scalar base; each gather is one
    // coalesced 256B transaction (uniform base + lane*4).
    float e[NUM_FACTORS];
#pragma unroll
    for (int i = 0; i < NUM_FACTORS; ++i) {
        unsigned ii = (unsigned)__builtin_amdgcn_readlane(myidx, i);
        e[i] = emb_table[(size_t)(ii * (unsigned)EMB_DIM) + (unsigned)lane];
    }

    // acc = sum_{i<j} W[i,j] * e_i[d] * e_j[d] for d = lane.
    // W[] is wave-uniform constant-indexed -> s_load; FMA uses SGPR operand.
    float acc = 0.0f;
#pragma unroll
    for (int i = 0; i < NUM_FACTORS - 1; ++i) {
        float ti = 0.0f;
#pragma unroll
        for (int j = i + 1; j < NUM_FACTORS; ++j) {
            ti = fmaf(W[i * NUM_FACTORS + j], e[j], ti);
        }
        acc = fmaf(e[i], ti, acc);
    }

    // Butterfly-sum interaction partials (all 64 lanes) + bias partials
    // (lanes < 39) in one pass.
    float total = acc + bpart;
#pragma unroll
    for (int off = 32; off > 0; off >>= 1)
        total += __shfl_xor(total, off);

    if (lane == 0) out[row] = w0[0] + total;
}

extern "C" void kernel_launch(void* const* d_in, const int* in_sizes, int n_in,
                              void* d_out, int out_size, void* d_ws, size_t ws_size,
                              hipStream_t stream) {
    const int*   x          = (const int*)d_in[0];
    const float* w0         = (const float*)d_in[1];
    const float* bias_table = (const float*)d_in[2];
    const float* emb_table  = (const float*)d_in[3];
    const float* W          = (const float*)d_in[4];
    float* out = (float*)d_out;

    const int batch = out_size;  // 16384
    const int grid = (batch + ROWS_PER_BLOCK - 1) / ROWS_PER_BLOCK;
    // 4 identical idempotent launches: dur_us = overhead + 4*T_kernel.
    for (int rep = 0; rep < 4; ++rep) {
        fwfm_kernel<<<grid, 256, 0, stream>>>(x, w0, bias_table, emb_table, W, out, batch);
    }
}

// Round 4
// 332.653 us; speedup vs baseline: 1.3584x; 1.3584x over previous
//
#include <hip/hip_runtime.h>

#define NUM_FACTORS 39
#define EMB_DIM 64
#define ROWS_PER_BLOCK 4   // 4 waves of 64 = 256 threads

// Final config (round-2 body, single launch). Calibration (R3, 4x launch)
// measured T_kernel ~= 39.3 us vs ~26 us ideal-HBM gather floor; repeat
// launches with L3-warm table run at the same rate -> bound by the random
// 256B-granule gather service rate (~4.3 TB/s), not cold fetches. dur_us
// is dominated by ~295 us of harness reset traffic outside our control.
__global__ __launch_bounds__(256, 8) void fwfm_kernel(
    const int* __restrict__ x,            // (B, 39) int32
    const float* __restrict__ w0,         // (1,)
    const float* __restrict__ bias_table, // (1M, 1)
    const float* __restrict__ emb_table,  // (1M, 64)
    const float* __restrict__ W,          // (39, 39)
    float* __restrict__ out,              // (B,)
    int batch)
{
    const int lane = threadIdx.x & 63;
    const int wave = threadIdx.x >> 6;
    const int row  = blockIdx.x * ROWS_PER_BLOCK + wave;
    if (row >= batch) return;

    // Lane i (i<39) loads this row's i-th field index and its bias.
    int myidx = 0;
    float bpart = 0.0f;
    if (lane < NUM_FACTORS) {
        myidx = x[row * NUM_FACTORS + lane];
        bpart = bias_table[myidx];
    }

    // Gather embeddings: e[i] = emb_table[idx_i][lane].
    // readlane -> SGPR row index -> scalar base; each gather is one
    // coalesced 256B transaction (uniform base + lane*4). All 39 loads are
    // independent -> full MLP per wave.
    float e[NUM_FACTORS];
#pragma unroll
    for (int i = 0; i < NUM_FACTORS; ++i) {
        unsigned ii = (unsigned)__builtin_amdgcn_readlane(myidx, i);
        e[i] = emb_table[(size_t)(ii * (unsigned)EMB_DIM) + (unsigned)lane];
    }

    // acc = sum_{i<j} W[i,j] * e_i[d] * e_j[d] for d = lane.
    // W[] is wave-uniform constant-indexed -> s_load; FMA uses SGPR operand.
    float acc = 0.0f;
#pragma unroll
    for (int i = 0; i < NUM_FACTORS - 1; ++i) {
        float ti = 0.0f;
#pragma unroll
        for (int j = i + 1; j < NUM_FACTORS; ++j) {
            ti = fmaf(W[i * NUM_FACTORS + j], e[j], ti);
        }
        acc = fmaf(e[i], ti, acc);
    }

    // Butterfly-sum interaction partials (all 64 lanes) + bias partials
    // (lanes < 39) in one pass.
    float total = acc + bpart;
#pragma unroll
    for (int off = 32; off > 0; off >>= 1)
        total += __shfl_xor(total, off);

    if (lane == 0) out[row] = w0[0] + total;
}

extern "C" void kernel_launch(void* const* d_in, const int* in_sizes, int n_in,
                              void* d_out, int out_size, void* d_ws, size_t ws_size,
                              hipStream_t stream) {
    const int*   x          = (const int*)d_in[0];
    const float* w0         = (const float*)d_in[1];
    const float* bias_table = (const float*)d_in[2];
    const float* emb_table  = (const float*)d_in[3];
    const float* W          = (const float*)d_in[4];
    float* out = (float*)d_out;

    const int batch = out_size;  // 16384
    const int grid = (batch + ROWS_PER_BLOCK - 1) / ROWS_PER_BLOCK;
    fwfm_kernel<<<grid, 256, 0, stream>>>(x, w0, bias_table, emb_table, W, out, batch);
}